// Round 15
// baseline (161.459 us; speedup 1.0000x reference)
//
#include <hip/hip_runtime.h>
#include <math.h>

// Problem constants
#define NB     32
#define DIM    64
#define HW     4096
#define DHW    (DIM * HW)           // 262144
#define N_ROWS (NB * HW)            // 131072
#define K_CODES 1024

#define Q_ELEMS  (NB * DIM * HW)    // 8388608
#define LOSS_OFF Q_ELEMS
#define IDX_OFF  (Q_ELEMS + 1)

#define ROWS       64               // rows per block
#define MAIN_BLOCKS (N_ROWS / ROWS) // 2048
#define MARGIN     6e-3f
#define CAND_CAP   64

// Packed codebook: per 16-code group g, a 2112B record:
//   [lane*32 .. lane*32+16) : b0 frag (bf16(e), dims lg*8..lg*8+8) code g*16+l15
//   [lane*32+16 .. +32)     : b1 frag (bf16(e), dims 32+lg*8..)
//   [2048 + l15*4)          : e2 of code g*16+l15 (f32)
// where lane = lg*16 + l15. Wave loads are fully coalesced (1KB contiguous).
#define PK_STRIDE 2112

typedef __attribute__((ext_vector_type(8))) short short8;
typedef __attribute__((ext_vector_type(4))) float f32x4;

__device__ __forceinline__ ushort f2bf_rne(float f) {
    unsigned u = __float_as_uint(f);
    u = (u + 0x7FFFu + ((u >> 16) & 1u)) >> 16;
    return (ushort)u;
}

// ---------------------------------------------------------------------------
// Prep: e2[k] (numpy pairwise-8 order) + bf16 codebook, in packed group order.
// Also zeroes the loss slot, which vq_main uses as a device-scope ticket.
__global__ void vq_prep(const float* __restrict__ emb, char* __restrict__ pk,
                        float* __restrict__ out) {
    int k = blockIdx.x * blockDim.x + threadIdx.x;
    if (k == 0) *(unsigned*)(out + LOSS_OFF) = 0u;       // ticket init (every launch)
    if (k >= K_CODES) return;
    const float* e = emb + k * DIM;
    float r[8];
#pragma unroll
    for (int j = 0; j < 8; ++j) r[j] = __fmul_rn(e[j], e[j]);
#pragma unroll
    for (int m = 1; m < 8; ++m) {
#pragma unroll
        for (int j = 0; j < 8; ++j)
            r[j] = __fadd_rn(r[j], __fmul_rn(e[8 * m + j], e[8 * m + j]));
    }
    const float e2v =
        __fadd_rn(__fadd_rn(__fadd_rn(r[0], r[1]), __fadd_rn(r[2], r[3])),
                  __fadd_rn(__fadd_rn(r[4], r[5]), __fadd_rn(r[6], r[7])));

    char* gb = pk + (size_t)(k >> 4) * PK_STRIDE;
    const int l15k = k & 15;
    *(float*)(gb + 2048 + l15k * 4) = e2v;
#pragma unroll
    for (int lg = 0; lg < 4; ++lg) {
        ushort* dst = (ushort*)(gb + (lg * 16 + l15k) * 32);
#pragma unroll
        for (int j = 0; j < 8; ++j) {
            dst[j]     = f2bf_rne(e[lg * 8 + j]);        // b0: dims lg*8+j
            dst[8 + j] = f2bf_rne(e[32 + lg * 8 + j]);   // b1: dims 32+lg*8+j
        }
    }
}

// ---------------------------------------------------------------------------
// Main: 64 rows x 1024 codes per block. Round-14 structure verbatim; ONE
// change: the loss reduction is fused via a last-block ticket on the loss
// slot (removes the vq_final launch). Reduction order bit-identical to the
// old vq_final. (256,4) is the ONLY proven no-spill bound for this live set.
__global__ __launch_bounds__(256, 4) void vq_main(
    const float* __restrict__ in, const float* __restrict__ emb,
    const char* __restrict__ pk,
    float* __restrict__ out, float* __restrict__ partial)
{
    __shared__ __align__(16) float Xf[DIM][ROWS];        // 16 KB, [d][r]
    __shared__ float x2s[ROWS];
    __shared__ float wmin[4][ROWS];                      // reused as s[256] at end
    __shared__ unsigned cnt[ROWS];
    __shared__ ushort cand[ROWS][CAND_CAP];              // 8 KB
    __shared__ int idxs[ROWS];
    __shared__ float lred[4];
    __shared__ unsigned ticket_s;

    const int t   = threadIdx.x;
    const int w   = t >> 6;
    const int l   = t & 63;
    const int b   = blockIdx.x >> 6;
    const int hw0 = (blockIdx.x & 63) * ROWS;
    const long n0 = (long)b * HW + hw0;
    const float* inb = in + (size_t)b * DHW + hw0;

    // ---- Stage X[d][r] via async global->LDS (linear dest) -----------------
    {
        const int dl = l >> 4;            // d offset within 4-line packet
        const int c4 = (l & 15) * 4;      // hw offset (floats)
#pragma unroll
        for (int i = 0; i < 4; ++i) {
            const int d0 = w * 16 + i * 4;                 // wave-uniform
            const float* src = inb + (size_t)(d0 + dl) * HW + c4;
            __builtin_amdgcn_global_load_lds(
                (const __attribute__((address_space(1))) void*)src,
                (__attribute__((address_space(3))) void*)&Xf[d0][0],
                16, 0, 0);
        }
        if (t < ROWS) cnt[t] = 0;
    }
    __syncthreads();

    // ---- x2 per row (numpy pairwise-8, bit-identical to round-1 kernel) ----
    if (t < ROWS) {
        float r8[8];
#pragma unroll
        for (int j = 0; j < 8; ++j) {
            const float v = Xf[j][t];
            r8[j] = __fmul_rn(v, v);
        }
#pragma unroll
        for (int m = 1; m < 8; ++m) {
#pragma unroll
            for (int j = 0; j < 8; ++j) {
                const float v = Xf[8 * m + j][t];
                r8[j] = __fadd_rn(r8[j], __fmul_rn(v, v));
            }
        }
        x2s[t] = __fadd_rn(__fadd_rn(__fadd_rn(r8[0], r8[1]), __fadd_rn(r8[2], r8[3])),
                           __fadd_rn(__fadd_rn(r8[4], r8[5]), __fadd_rn(r8[6], r8[7])));
    }

    // ---- A fragments in registers (bf16, same f2bf_rne values as before) ---
    const int lg  = l >> 4;
    const int l15 = l & 15;
    short8 afr[4][2];
#pragma unroll
    for (int rfi = 0; rfi < 4; ++rfi) {
#pragma unroll
        for (int kf = 0; kf < 2; ++kf) {
            const int r  = rfi * 16 + l15;
            const int d0 = (kf * 4 + lg) * 8;
            short8 a;
#pragma unroll
            for (int j = 0; j < 8; ++j) a[j] = (short)f2bf_rne(Xf[d0 + j][r]);
            afr[rfi][kf] = a;
        }
    }

    const int loff = l * 32;               // per-lane byte offset, loop-invariant

    // ---- Pass 1: per-row min of approx score -------------------------------
    float vmin[4][4];
#pragma unroll
    for (int i = 0; i < 4; ++i)
#pragma unroll
        for (int j = 0; j < 4; ++j) vmin[i][j] = INFINITY;

    for (int iter = 0; iter < 4; ++iter) {
#pragma unroll
        for (int cfi = 0; cfi < 4; ++cfi) {
            const int g = iter * 16 + w * 4 + cfi;         // wave-uniform group
            const char* gb = pk + (size_t)g * PK_STRIDE;
            const short8 b0 = *(const short8*)(gb + loff);
            const short8 b1 = *(const short8*)(gb + loff + 16);
            const float e2c = *(const float*)(gb + 2048 + l15 * 4);
#pragma unroll
            for (int rfi = 0; rfi < 4; ++rfi) {
                f32x4 c = {0.f, 0.f, 0.f, 0.f};
                c = __builtin_amdgcn_mfma_f32_16x16x32_bf16(afr[rfi][0], b0, c, 0, 0, 0);
                c = __builtin_amdgcn_mfma_f32_16x16x32_bf16(afr[rfi][1], b1, c, 0, 0, 0);
#pragma unroll
                for (int j = 0; j < 4; ++j) {
                    const float av = __fmaf_rn(-2.0f, c[j], e2c);
                    vmin[rfi][j] = fminf(vmin[rfi][j], av);
                }
            }
        }
    }
#pragma unroll
    for (int m = 1; m < 16; m <<= 1) {
#pragma unroll
        for (int rfi = 0; rfi < 4; ++rfi)
#pragma unroll
            for (int j = 0; j < 4; ++j)
                vmin[rfi][j] = fminf(vmin[rfi][j], __shfl_xor(vmin[rfi][j], m, 64));
    }
    if (l15 == 0) {
#pragma unroll
        for (int rfi = 0; rfi < 4; ++rfi)
#pragma unroll
            for (int j = 0; j < 4; ++j)
                wmin[w][rfi * 16 + lg * 4 + j] = vmin[rfi][j];
    }
    __syncthreads();

    // ---- Pass 2: candidate collection (bound from broadcast wmin reads) ----
    {
        float bound[4][4];
#pragma unroll
        for (int rfi = 0; rfi < 4; ++rfi)
#pragma unroll
            for (int j = 0; j < 4; ++j) {
                const int row = rfi * 16 + lg * 4 + j;
                bound[rfi][j] = fminf(fminf(wmin[0][row], wmin[1][row]),
                                      fminf(wmin[2][row], wmin[3][row])) + MARGIN;
            }

        for (int iter = 0; iter < 4; ++iter) {
#pragma unroll
            for (int cfi = 0; cfi < 4; ++cfi) {
                const int g = iter * 16 + w * 4 + cfi;
                const char* gb = pk + (size_t)g * PK_STRIDE;
                const short8 b0 = *(const short8*)(gb + loff);
                const short8 b1 = *(const short8*)(gb + loff + 16);
                const float e2c = *(const float*)(gb + 2048 + l15 * 4);
                const int code = g * 16 + l15;
#pragma unroll
                for (int rfi = 0; rfi < 4; ++rfi) {
                    f32x4 c = {0.f, 0.f, 0.f, 0.f};
                    c = __builtin_amdgcn_mfma_f32_16x16x32_bf16(afr[rfi][0], b0, c, 0, 0, 0);
                    c = __builtin_amdgcn_mfma_f32_16x16x32_bf16(afr[rfi][1], b1, c, 0, 0, 0);
#pragma unroll
                    for (int j = 0; j < 4; ++j) {
                        const float av = __fmaf_rn(-2.0f, c[j], e2c);
                        if (av <= bound[rfi][j]) {
                            const int row = rfi * 16 + lg * 4 + j;
                            const unsigned slot = atomicAdd(&cnt[row], 1u);
                            if (slot < CAND_CAP) cand[row][slot] = (ushort)code;
                        }
                    }
                }
            }
        }
    }
    __syncthreads();

    // ---- Exact fp32 rescore, 4 lanes per row (replicated np op order) ------
    {
        const int q = t & 3;
        const int r = t >> 2;
        int nc = (int)cnt[r];
        if (nc > CAND_CAP) nc = CAND_CAP;
        const float x2v = x2s[r];
        float best = INFINITY;
        int   bk   = K_CODES;
        for (int ci = q; ci < nc; ci += 4) {
            const int k = cand[r][ci];
            const float* ek = emb + k * DIM;
            float dot = 0.0f;
#pragma unroll
            for (int dd = 0; dd < DIM; dd += 4) {
                const float4 ev = *(const float4*)(ek + dd);
                dot = __fmaf_rn(Xf[dd + 0][r], ev.x, dot);
                dot = __fmaf_rn(Xf[dd + 1][r], ev.y, dot);
                dot = __fmaf_rn(Xf[dd + 2][r], ev.z, dot);
                dot = __fmaf_rn(Xf[dd + 3][r], ev.w, dot);
            }
            const float e2k =
                *(const float*)(pk + (size_t)(k >> 4) * PK_STRIDE + 2048 + (k & 15) * 4);
            const float dist = __fadd_rn(__fadd_rn(x2v, e2k), -2.0f * dot);
            if (dist < best || (dist == best && k < bk)) { best = dist; bk = k; }
        }
#pragma unroll
        for (int m = 1; m < 4; m <<= 1) {
            const float ob = __shfl_xor(best, m, 64);
            const int   ok = __shfl_xor(bk,   m, 64);
            if (ob < best || (ob == best && ok < bk)) { best = ob; bk = ok; }
        }
        if (q == 0) idxs[r] = bk;
    }
    __syncthreads();

    // ---- coalesced index writes (wave 0) -----------------------------------
    if (t < ROWS) out[IDX_OFF + n0 + t] = (float)idxs[t];

    // ---- quantized_st writes + fused loss (all 256 threads) ----------------
    {
        const int r  = l;          // row = lane (coalesced stores)
        const int dg = w;          // wave covers 16 d-lines
        const float* eq = emb + idxs[r] * DIM + dg * 16;
        float* ob = out + (size_t)b * DHW + hw0 + r;
        float ls = 0.0f;
#pragma unroll
        for (int i = 0; i < 4; ++i) {
            const float4 qv = *(const float4*)(eq + i * 4);
            const float qa[4] = {qv.x, qv.y, qv.z, qv.w};
#pragma unroll
            for (int c2 = 0; c2 < 4; ++c2) {
                const int d = dg * 16 + i * 4 + c2;
                const float xv = Xf[d][r];
                const float df = __fsub_rn(qa[c2], xv);
                ls = __fadd_rn(ls, __fmul_rn(df, df));
                ob[(size_t)d * HW] = __fadd_rn(xv, df);
            }
        }
#pragma unroll
        for (int off = 32; off > 0; off >>= 1) ls += __shfl_down(ls, off, 64);
        if (l == 0) lred[w] = ls;
    }
    __syncthreads();
    if (t == 0) {
        partial[blockIdx.x] = __fadd_rn(__fadd_rn(lred[0], lred[1]),
                                        __fadd_rn(lred[2], lred[3]));
        __threadfence();                               // release partial store
        ticket_s = atomicAdd((unsigned*)(out + LOSS_OFF), 1u);
    }
    __syncthreads();

    // ---- last block: final loss reduction (bit-identical to old vq_final) --
    if (ticket_s == MAIN_BLOCKS - 1) {
        __threadfence();                               // acquire partials
        float* s = &wmin[0][0];                        // reuse 256-float LDS
        float a = 0.0f;
#pragma unroll
        for (int i = 0; i < 8; ++i) a += partial[t + 256 * i];
        s[t] = a;
        __syncthreads();
        for (int off = 128; off > 0; off >>= 1) {
            if (t < off) s[t] += s[t + off];
            __syncthreads();
        }
        if (t == 0) out[LOSS_OFF] = 0.25f * s[0] / (float)Q_ELEMS;
    }
}

// ---------------------------------------------------------------------------
extern "C" void kernel_launch(void* const* d_in, const int* in_sizes, int n_in,
                              void* d_out, int out_size, void* d_ws, size_t ws_size,
                              hipStream_t stream) {
    const float* in  = (const float*)d_in[0];
    const float* emb = (const float*)d_in[1];
    float* out = (float*)d_out;
    float* ws  = (float*)d_ws;
    float* partial = ws;                        // 2048 floats
    char*  pk      = (char*)(ws + 2048);        // 64 * 2112 B = 135168 B

    vq_prep<<<4, 256, 0, stream>>>(emb, pk, out);
    vq_main<<<MAIN_BLOCKS, 256, 0, stream>>>(in, emb, pk, out, partial);
}

// Round 16
// 110.664 us; speedup vs baseline: 1.4590x; 1.4590x over previous
//
#include <hip/hip_runtime.h>
#include <math.h>

// Problem constants
#define NB     32
#define DIM    64
#define HW     4096
#define DHW    (DIM * HW)           // 262144
#define N_ROWS (NB * HW)            // 131072
#define K_CODES 1024

#define Q_ELEMS  (NB * DIM * HW)    // 8388608
#define LOSS_OFF Q_ELEMS
#define IDX_OFF  (Q_ELEMS + 1)

#define ROWS       64               // rows per block
#define MAIN_BLOCKS (N_ROWS / ROWS) // 2048
#define MARGIN     6e-3f
#define CAND_CAP   64

// Packed codebook: per 16-code group g, a 2112B record:
//   [lane*32 .. lane*32+16) : b0 frag (bf16(e), dims lg*8..lg*8+8) code g*16+l15
//   [lane*32+16 .. +32)     : b1 frag (bf16(e), dims 32+lg*8..)
//   [2048 + l15*4)          : e2 of code g*16+l15 (f32)
// where lane = lg*16 + l15. Wave loads are fully coalesced (1KB contiguous).
#define PK_STRIDE 2112

typedef __attribute__((ext_vector_type(8))) short short8;
typedef __attribute__((ext_vector_type(4))) float f32x4;

__device__ __forceinline__ ushort f2bf_rne(float f) {
    unsigned u = __float_as_uint(f);
    u = (u + 0x7FFFu + ((u >> 16) & 1u)) >> 16;
    return (ushort)u;
}

// ---------------------------------------------------------------------------
// Prep: e2[k] (numpy pairwise-8 order) + bf16 codebook, in packed group order.
__global__ void vq_prep(const float* __restrict__ emb, char* __restrict__ pk) {
    int k = blockIdx.x * blockDim.x + threadIdx.x;
    if (k >= K_CODES) return;
    const float* e = emb + k * DIM;
    float r[8];
#pragma unroll
    for (int j = 0; j < 8; ++j) r[j] = __fmul_rn(e[j], e[j]);
#pragma unroll
    for (int m = 1; m < 8; ++m) {
#pragma unroll
        for (int j = 0; j < 8; ++j)
            r[j] = __fadd_rn(r[j], __fmul_rn(e[8 * m + j], e[8 * m + j]));
    }
    const float e2v =
        __fadd_rn(__fadd_rn(__fadd_rn(r[0], r[1]), __fadd_rn(r[2], r[3])),
                  __fadd_rn(__fadd_rn(r[4], r[5]), __fadd_rn(r[6], r[7])));

    char* gb = pk + (size_t)(k >> 4) * PK_STRIDE;
    const int l15 = k & 15;
    *(float*)(gb + 2048 + l15 * 4) = e2v;
#pragma unroll
    for (int lg = 0; lg < 4; ++lg) {
        ushort* dst = (ushort*)(gb + (lg * 16 + l15) * 32);
#pragma unroll
        for (int j = 0; j < 8; ++j) {
            dst[j]     = f2bf_rne(e[lg * 8 + j]);        // b0: dims lg*8+j
            dst[8 + j] = f2bf_rne(e[32 + lg * 8 + j]);   // b1: dims 32+lg*8+j
        }
    }
}

// ---------------------------------------------------------------------------
// Main: 64 rows x 1024 codes per block — round-12 best-measured kernel
// (110.8 us). Packed coalesced codebook; fma-based scoring (e2 OFF the MFMA
// issue path — r13 lesson); separate vq_final launch (r15 lesson: per-block
// device-scope fences cost ~10x a kernel launch on 8 XCDs).
// (256,4) is the ONLY proven no-spill bound for this live set.
__global__ __launch_bounds__(256, 4) void vq_main(
    const float* __restrict__ in, const float* __restrict__ emb,
    const char* __restrict__ pk,
    float* __restrict__ out, float* __restrict__ partial)
{
    __shared__ __align__(16) float Xf[DIM][ROWS];        // 16 KB, [d][r]
    __shared__ float x2s[ROWS];
    __shared__ float wmin[4][ROWS];
    __shared__ float minap[ROWS];
    __shared__ unsigned cnt[ROWS];
    __shared__ ushort cand[ROWS][CAND_CAP];              // 8 KB
    __shared__ int idxs[ROWS];
    __shared__ float lred[4];

    const int t   = threadIdx.x;
    const int w   = t >> 6;
    const int l   = t & 63;
    const int b   = blockIdx.x >> 6;
    const int hw0 = (blockIdx.x & 63) * ROWS;
    const long n0 = (long)b * HW + hw0;
    const float* inb = in + (size_t)b * DHW + hw0;

    // ---- Stage X[d][r] via async global->LDS (linear dest) -----------------
    {
        const int dl = l >> 4;            // d offset within 4-line packet
        const int c4 = (l & 15) * 4;      // hw offset (floats)
#pragma unroll
        for (int i = 0; i < 4; ++i) {
            const int d0 = w * 16 + i * 4;                 // wave-uniform
            const float* src = inb + (size_t)(d0 + dl) * HW + c4;
            __builtin_amdgcn_global_load_lds(
                (const __attribute__((address_space(1))) void*)src,
                (__attribute__((address_space(3))) void*)&Xf[d0][0],
                16, 0, 0);
        }
        if (t < ROWS) cnt[t] = 0;
    }
    __syncthreads();

    // ---- x2 per row (numpy pairwise-8, bit-identical to round-1 kernel) ----
    if (t < ROWS) {
        float r8[8];
#pragma unroll
        for (int j = 0; j < 8; ++j) {
            const float v = Xf[j][t];
            r8[j] = __fmul_rn(v, v);
        }
#pragma unroll
        for (int m = 1; m < 8; ++m) {
#pragma unroll
            for (int j = 0; j < 8; ++j) {
                const float v = Xf[8 * m + j][t];
                r8[j] = __fadd_rn(r8[j], __fmul_rn(v, v));
            }
        }
        x2s[t] = __fadd_rn(__fadd_rn(__fadd_rn(r8[0], r8[1]), __fadd_rn(r8[2], r8[3])),
                           __fadd_rn(__fadd_rn(r8[4], r8[5]), __fadd_rn(r8[6], r8[7])));
    }

    // ---- A fragments in registers (bf16, same f2bf_rne values as before) ---
    const int lg  = l >> 4;
    const int l15 = l & 15;
    short8 afr[4][2];
#pragma unroll
    for (int rfi = 0; rfi < 4; ++rfi) {
#pragma unroll
        for (int kf = 0; kf < 2; ++kf) {
            const int r  = rfi * 16 + l15;
            const int d0 = (kf * 4 + lg) * 8;
            short8 a;
#pragma unroll
            for (int j = 0; j < 8; ++j) a[j] = (short)f2bf_rne(Xf[d0 + j][r]);
            afr[rfi][kf] = a;
        }
    }

    const int loff = l * 32;               // per-lane byte offset, loop-invariant

    // ---- Pass 1: per-row min of approx score -------------------------------
    float vmin[4][4];
#pragma unroll
    for (int i = 0; i < 4; ++i)
#pragma unroll
        for (int j = 0; j < 4; ++j) vmin[i][j] = INFINITY;

    for (int iter = 0; iter < 4; ++iter) {
#pragma unroll
        for (int cfi = 0; cfi < 4; ++cfi) {
            const int g = iter * 16 + w * 4 + cfi;         // wave-uniform group
            const char* gb = pk + (size_t)g * PK_STRIDE;
            const short8 b0 = *(const short8*)(gb + loff);
            const short8 b1 = *(const short8*)(gb + loff + 16);
            const float e2c = *(const float*)(gb + 2048 + l15 * 4);
#pragma unroll
            for (int rfi = 0; rfi < 4; ++rfi) {
                f32x4 c = {0.f, 0.f, 0.f, 0.f};
                c = __builtin_amdgcn_mfma_f32_16x16x32_bf16(afr[rfi][0], b0, c, 0, 0, 0);
                c = __builtin_amdgcn_mfma_f32_16x16x32_bf16(afr[rfi][1], b1, c, 0, 0, 0);
#pragma unroll
                for (int j = 0; j < 4; ++j) {
                    const float av = __fmaf_rn(-2.0f, c[j], e2c);
                    vmin[rfi][j] = fminf(vmin[rfi][j], av);
                }
            }
        }
    }
#pragma unroll
    for (int m = 1; m < 16; m <<= 1) {
#pragma unroll
        for (int rfi = 0; rfi < 4; ++rfi)
#pragma unroll
            for (int j = 0; j < 4; ++j)
                vmin[rfi][j] = fminf(vmin[rfi][j], __shfl_xor(vmin[rfi][j], m, 64));
    }
    if (l15 == 0) {
#pragma unroll
        for (int rfi = 0; rfi < 4; ++rfi)
#pragma unroll
            for (int j = 0; j < 4; ++j)
                wmin[w][rfi * 16 + lg * 4 + j] = vmin[rfi][j];
    }
    __syncthreads();
    if (t < ROWS)
        minap[t] = fminf(fminf(wmin[0][t], wmin[1][t]),
                         fminf(wmin[2][t], wmin[3][t])) + MARGIN;
    __syncthreads();

    // ---- Pass 2: candidate collection --------------------------------------
    {
        float bound[4][4];
#pragma unroll
        for (int rfi = 0; rfi < 4; ++rfi)
#pragma unroll
            for (int j = 0; j < 4; ++j)
                bound[rfi][j] = minap[rfi * 16 + lg * 4 + j];

        for (int iter = 0; iter < 4; ++iter) {
#pragma unroll
            for (int cfi = 0; cfi < 4; ++cfi) {
                const int g = iter * 16 + w * 4 + cfi;
                const char* gb = pk + (size_t)g * PK_STRIDE;
                const short8 b0 = *(const short8*)(gb + loff);
                const short8 b1 = *(const short8*)(gb + loff + 16);
                const float e2c = *(const float*)(gb + 2048 + l15 * 4);
                const int code = g * 16 + l15;
#pragma unroll
                for (int rfi = 0; rfi < 4; ++rfi) {
                    f32x4 c = {0.f, 0.f, 0.f, 0.f};
                    c = __builtin_amdgcn_mfma_f32_16x16x32_bf16(afr[rfi][0], b0, c, 0, 0, 0);
                    c = __builtin_amdgcn_mfma_f32_16x16x32_bf16(afr[rfi][1], b1, c, 0, 0, 0);
#pragma unroll
                    for (int j = 0; j < 4; ++j) {
                        const float av = __fmaf_rn(-2.0f, c[j], e2c);
                        if (av <= bound[rfi][j]) {
                            const int row = rfi * 16 + lg * 4 + j;
                            const unsigned slot = atomicAdd(&cnt[row], 1u);
                            if (slot < CAND_CAP) cand[row][slot] = (ushort)code;
                        }
                    }
                }
            }
        }
    }
    __syncthreads();

    // ---- Exact fp32 rescore, 4 lanes per row (replicated np op order) ------
    {
        const int q = t & 3;
        const int r = t >> 2;
        int nc = (int)cnt[r];
        if (nc > CAND_CAP) nc = CAND_CAP;
        const float x2v = x2s[r];
        float best = INFINITY;
        int   bk   = K_CODES;
        for (int ci = q; ci < nc; ci += 4) {
            const int k = cand[r][ci];
            const float* ek = emb + k * DIM;
            float dot = 0.0f;
#pragma unroll
            for (int dd = 0; dd < DIM; dd += 4) {
                const float4 ev = *(const float4*)(ek + dd);
                dot = __fmaf_rn(Xf[dd + 0][r], ev.x, dot);
                dot = __fmaf_rn(Xf[dd + 1][r], ev.y, dot);
                dot = __fmaf_rn(Xf[dd + 2][r], ev.z, dot);
                dot = __fmaf_rn(Xf[dd + 3][r], ev.w, dot);
            }
            const float e2k =
                *(const float*)(pk + (size_t)(k >> 4) * PK_STRIDE + 2048 + (k & 15) * 4);
            const float dist = __fadd_rn(__fadd_rn(x2v, e2k), -2.0f * dot);
            if (dist < best || (dist == best && k < bk)) { best = dist; bk = k; }
        }
#pragma unroll
        for (int m = 1; m < 4; m <<= 1) {
            const float ob = __shfl_xor(best, m, 64);
            const int   ok = __shfl_xor(bk,   m, 64);
            if (ob < best || (ob == best && ok < bk)) { best = ob; bk = ok; }
        }
        if (q == 0) idxs[r] = bk;
    }
    __syncthreads();

    // ---- coalesced index writes (wave 0) -----------------------------------
    if (t < ROWS) out[IDX_OFF + n0 + t] = (float)idxs[t];

    // ---- quantized_st writes + fused loss (all 256 threads) ----------------
    {
        const int r  = l;          // row = lane (coalesced stores)
        const int dg = w;          // wave covers 16 d-lines
        const float* eq = emb + idxs[r] * DIM + dg * 16;
        float* ob = out + (size_t)b * DHW + hw0 + r;
        float ls = 0.0f;
#pragma unroll
        for (int i = 0; i < 4; ++i) {
            const float4 qv = *(const float4*)(eq + i * 4);
            const float qa[4] = {qv.x, qv.y, qv.z, qv.w};
#pragma unroll
            for (int c2 = 0; c2 < 4; ++c2) {
                const int d = dg * 16 + i * 4 + c2;
                const float xv = Xf[d][r];
                const float df = __fsub_rn(qa[c2], xv);
                ls = __fadd_rn(ls, __fmul_rn(df, df));
                ob[(size_t)d * HW] = __fadd_rn(xv, df);
            }
        }
#pragma unroll
        for (int off = 32; off > 0; off >>= 1) ls += __shfl_down(ls, off, 64);
        if (l == 0) lred[w] = ls;
    }
    __syncthreads();
    if (t == 0)
        partial[blockIdx.x] = __fadd_rn(__fadd_rn(lred[0], lred[1]),
                                        __fadd_rn(lred[2], lred[3]));
}

// ---------------------------------------------------------------------------
__global__ __launch_bounds__(256) void vq_final(const float* __restrict__ partial,
                                                float* __restrict__ out) {
    __shared__ float s[256];
    const int t = threadIdx.x;
    float a = 0.0f;
#pragma unroll
    for (int i = 0; i < 8; ++i) a += partial[t + 256 * i];
    s[t] = a;
    __syncthreads();
    for (int off = 128; off > 0; off >>= 1) {
        if (t < off) s[t] += s[t + off];
        __syncthreads();
    }
    if (t == 0) out[LOSS_OFF] = 0.25f * s[0] / (float)Q_ELEMS;
}

// ---------------------------------------------------------------------------
extern "C" void kernel_launch(void* const* d_in, const int* in_sizes, int n_in,
                              void* d_out, int out_size, void* d_ws, size_t ws_size,
                              hipStream_t stream) {
    const float* in  = (const float*)d_in[0];
    const float* emb = (const float*)d_in[1];
    float* out = (float*)d_out;
    float* ws  = (float*)d_ws;
    float* partial = ws;                        // 2048 floats
    char*  pk      = (char*)(ws + 2048);        // 64 * 2112 B = 135168 B

    vq_prep<<<4, 256, 0, stream>>>(emb, pk);
    vq_main<<<MAIN_BLOCKS, 256, 0, stream>>>(in, emb, pk, out, partial);
    vq_final<<<1, 256, 0, stream>>>(partial, out);
}